// Round 2
// baseline (776.240 us; speedup 1.0000x reference)
//
#include <hip/hip_runtime.h>
#include <hip/hip_bf16.h>

#define NS 8192
#define NE 4096
#define DIN 512
#define DK 64
#define DV 256
#define NCHUNK 16
#define CHUNK (NS / NCHUNK)   // 512
#define NTILE (CHUNK / 64)    // 8

typedef __attribute__((ext_vector_type(8))) short bf16x8;
typedef __attribute__((ext_vector_type(4))) short bf16x4;
typedef __attribute__((ext_vector_type(4))) float f32x4;
typedef __attribute__((ext_vector_type(8))) unsigned short ushort8;
typedef __attribute__((ext_vector_type(4))) unsigned short ushort4v;

#define L2E 1.44269504088896f

__device__ __forceinline__ unsigned short f2bf(float f) {
    union { float f; unsigned int u; } v; v.f = f;
    unsigned int u = v.u;
    unsigned int r = u + 0x7fffu + ((u >> 16) & 1u);   // RNE
    return (unsigned short)(r >> 16);
}

// ---------------------------------------------------------------------------
// proj: fused Q/K/V projections.  C = A(fp32,Mx512) @ B(fp32,512xN) -> bf16.
// blocks 0..63: Q = Y@Wq * 0.125*log2e -> Qb[4096][64]   (scores in log2 units)
// blocks 64..191: K = X@Wk            -> Kb[8192][64]
// blocks 192..703: V = X@Wv           -> Vt[256][8192]  (transposed epilogue)
// ---------------------------------------------------------------------------
union ProjSmem {
    struct { unsigned short As[64][40]; unsigned short Bst[64][40]; } s;
    unsigned short Ct[64][72];
};

__global__ __launch_bounds__(256, 4) void proj_kernel(
    const float* __restrict__ X, const float* __restrict__ Y,
    const float* __restrict__ Wq, const float* __restrict__ Wk,
    const float* __restrict__ Wv,
    unsigned short* __restrict__ Qb, unsigned short* __restrict__ Kb,
    unsigned short* __restrict__ Vt) {

    int b = blockIdx.x;
    const float* A; const float* B; unsigned short* out;
    int N, m0, n0; float scale; bool tr;
    if (b < 64)       { A = Y; B = Wq; out = Qb; N = 64;  m0 = b * 64;        n0 = 0;            scale = 0.125f * L2E; tr = false; }
    else if (b < 192) { A = X; B = Wk; out = Kb; N = 64;  m0 = (b - 64) * 64; n0 = 0;            scale = 1.0f;         tr = false; }
    else              { int bb = b - 192;
                        A = X; B = Wv; out = Vt; N = 256; m0 = (bb >> 2) * 64; n0 = (bb & 3) * 64; scale = 1.0f;       tr = true; }

    __shared__ ProjSmem sm;
    int tid = threadIdx.x;
    int lane = tid & 63, w = tid >> 6;
    int c = lane & 15, g = lane >> 4;
    int wr = w >> 1, wc = w & 1;

    f32x4 acc[2][2] = {};

    for (int kt = 0; kt < 16; ++kt) {
        int k0 = kt * 32;
        __syncthreads();
        #pragma unroll
        for (int it = 0; it < 2; ++it) {
            int idx = it * 256 + tid;
            {   // stage A tile: 64 rows x 32 k, fp32 -> bf16
                int r = idx >> 3, c4 = (idx & 7) * 4;
                float4 v = *(const float4*)&A[(size_t)(m0 + r) * DIN + k0 + c4];
                ushort4v t; t.x = f2bf(v.x); t.y = f2bf(v.y); t.z = f2bf(v.z); t.w = f2bf(v.w);
                *(ushort4v*)&sm.s.As[r][c4] = t;
            }
            {   // stage B tile transposed: Bst[n][k]
                int kk = idx >> 4, c4 = (idx & 15) * 4;
                float4 v = *(const float4*)&B[(size_t)(k0 + kk) * N + n0 + c4];
                sm.s.Bst[c4 + 0][kk] = f2bf(v.x);
                sm.s.Bst[c4 + 1][kk] = f2bf(v.y);
                sm.s.Bst[c4 + 2][kk] = f2bf(v.z);
                sm.s.Bst[c4 + 3][kk] = f2bf(v.w);
            }
        }
        __syncthreads();

        bf16x8 af[2], bfr[2];
        #pragma unroll
        for (int fr = 0; fr < 2; ++fr)
            af[fr] = *(const bf16x8*)&sm.s.As[wr * 32 + fr * 16 + c][8 * g];
        #pragma unroll
        for (int fc = 0; fc < 2; ++fc)
            bfr[fc] = *(const bf16x8*)&sm.s.Bst[wc * 32 + fc * 16 + c][8 * g];
        #pragma unroll
        for (int fr = 0; fr < 2; ++fr)
            #pragma unroll
            for (int fc = 0; fc < 2; ++fc)
                acc[fr][fc] = __builtin_amdgcn_mfma_f32_16x16x32_bf16(af[fr], bfr[fc], acc[fr][fc], 0, 0, 0);
    }

    if (!tr) {
        #pragma unroll
        for (int fr = 0; fr < 2; ++fr)
            #pragma unroll
            for (int fc = 0; fc < 2; ++fc)
                #pragma unroll
                for (int i = 0; i < 4; ++i) {
                    int row = wr * 32 + fr * 16 + 4 * g + i;
                    int col = wc * 32 + fc * 16 + c;
                    out[(size_t)(m0 + row) * N + n0 + col] = f2bf(acc[fr][fc][i] * scale);
                }
    } else {
        __syncthreads();
        #pragma unroll
        for (int fr = 0; fr < 2; ++fr)
            #pragma unroll
            for (int fc = 0; fc < 2; ++fc)
                #pragma unroll
                for (int i = 0; i < 4; ++i) {
                    int row = wr * 32 + fr * 16 + 4 * g + i;   // m (sample)
                    int col = wc * 32 + fc * 16 + c;           // n (vdim)
                    sm.Ct[col][row] = f2bf(acc[fr][fc][i]);
                }
        __syncthreads();
        int nl = tid >> 2, c16 = (tid & 3) * 16;
        ushort8 a0 = *(const ushort8*)&sm.Ct[nl][c16];
        ushort8 a1 = *(const ushort8*)&sm.Ct[nl][c16 + 8];
        *(ushort8*)&out[(size_t)(n0 + nl) * NS + m0 + c16] = a0;
        *(ushort8*)&out[(size_t)(n0 + nl) * NS + m0 + c16 + 8] = a1;
    }
}

// ---------------------------------------------------------------------------
// flash: S^T = K·Q^T per wave (16 edges).  XOR-swizzled LDS (T2), staging via
// global_load_lds w/ pre-swizzled source (rule #21), H prefetched 1 tile
// ahead into double-buffered regs (T14).  Partials: bf16-pair packed, v-major.
// grid: 1024 blocks = 64 edge-tiles x 16 sample-chunks.
// ---------------------------------------------------------------------------
__global__ __launch_bounds__(256, 3) void flash_kernel(
    const unsigned short* __restrict__ Qb, const unsigned short* __restrict__ Kb,
    const unsigned short* __restrict__ Vt, const int* __restrict__ H,
    unsigned int* __restrict__ pacc, float* __restrict__ pm, float* __restrict__ pl) {

    int bid = blockIdx.x;
    int eb = bid & 63, ch = bid >> 6;
    int e0 = eb * 64;
    int sbeg = ch * CHUNK;

    __shared__ unsigned short Ks[64 * 64];    // 8 KB, row stride 128B, XOR-swizzled
    __shared__ unsigned short Vts[256 * 64];  // 32 KB, row stride 128B, XOR-swizzled

    int tid = threadIdx.x, lane = tid & 63, w = tid >> 6;
    int c = lane & 15, g = lane >> 4;
    int eW = e0 + w * 16 + c;   // this lane's edge column

    bf16x8 qf[2];
    #pragma unroll
    for (int ks = 0; ks < 2; ++ks)
        qf[ks] = *(const bf16x8*)&Qb[(size_t)eW * DK + ks * 32 + 8 * g];

    f32x4 o[16] = {};
    float m = -1e30f, l = 0.0f;

    int hA[16], hB[16];

    // staging: linear LDS dest (wave-uniform base + lane*16B), source column
    // pre-swizzled by (row&7) so the swizzled read below sees the right data.
    auto stageKV = [&](int t) {
        int s0 = sbeg + t * 64;
        int cc = tid & 7;
        #pragma unroll
        for (int it = 0; it < 2; ++it) {
            int r = (it * 256 + tid) >> 3;
            int cs = cc ^ (r & 7);
            __builtin_amdgcn_global_load_lds(
                (const void*)&Kb[(size_t)(s0 + r) * DK + cs * 8],
                (void*)((char*)Ks + (it * 256 + w * 64) * 16), 16, 0, 0);
        }
        #pragma unroll
        for (int it = 0; it < 8; ++it) {
            int v = (it * 256 + tid) >> 3;
            int cs = cc ^ (v & 7);
            __builtin_amdgcn_global_load_lds(
                (const void*)&Vt[(size_t)v * NS + s0 + cs * 8],
                (void*)((char*)Vts + (it * 256 + w * 64) * 16), 16, 0, 0);
        }
    };

    auto issueH = [&](int (&hv)[16], int t) {
        int s0 = sbeg + t * 64;
        #pragma unroll
        for (int fr = 0; fr < 4; ++fr)
            #pragma unroll
            for (int i = 0; i < 4; ++i)
                hv[fr * 4 + i] = __builtin_nontemporal_load(
                    &H[(size_t)(s0 + fr * 16 + 4 * g + i) * NE + eW]);
    };

    auto compute = [&](const int (&hv)[16]) {
        // S^T tile: rows = samples, cols = this wave's 16 edges
        f32x4 st[4] = {};
        #pragma unroll
        for (int ks = 0; ks < 2; ++ks)
            #pragma unroll
            for (int fr = 0; fr < 4; ++fr) {
                int u = ((fr * 16 + c) * 64 + ks * 32 + 8 * g) ^ ((c & 7) << 3);
                bf16x8 a = *(const bf16x8*)&Ks[u];
                st[fr] = __builtin_amdgcn_mfma_f32_16x16x32_bf16(a, qf[ks], st[fr], 0, 0, 0);
            }

        // mask + per-edge tile max (reduce over g via shfl_xor 16/32)
        float pmax = -1e30f;
        #pragma unroll
        for (int fr = 0; fr < 4; ++fr)
            #pragma unroll
            for (int i = 0; i < 4; ++i) {
                float sv = hv[fr * 4 + i] ? st[fr][i] : -1e30f;
                st[fr][i] = sv;
                pmax = fmaxf(pmax, sv);
            }
        pmax = fmaxf(pmax, __shfl_xor(pmax, 16));
        pmax = fmaxf(pmax, __shfl_xor(pmax, 32));

        // defer-max rescale (THR=8 in log2 units -> P <= 256)
        if (!__all(pmax <= m + 8.0f)) {
            float mn = fmaxf(m, pmax);
            float al = exp2f(m - mn);
            l *= al;
            #pragma unroll
            for (int vb = 0; vb < 16; ++vb) o[vb] *= al;
            m = mn;
        }

        float lp = 0.0f;
        #pragma unroll
        for (int fr = 0; fr < 4; ++fr)
            #pragma unroll
            for (int i = 0; i < 4; ++i) {
                float e = exp2f(st[fr][i] - m);   // scores already in log2 units
                st[fr][i] = e;
                lp += e;
            }
        lp += __shfl_xor(lp, 16);
        lp += __shfl_xor(lp, 32);
        l += lp;

        // pack P to bf16 pairs (lane-local)
        unsigned int pk[8];
        #pragma unroll
        for (int fr = 0; fr < 4; ++fr)
            #pragma unroll
            for (int hf = 0; hf < 2; ++hf) {
                union { __hip_bfloat162 h; unsigned int u; } cv;
                cv.h = __float22bfloat162_rn(make_float2(st[fr][2 * hf], st[fr][2 * hf + 1]));
                pk[fr * 2 + hf] = cv.u;
            }

        // PV: out^T[v][e]; A = Vts rows (two b64 reads realize the k-slot perm)
        #pragma unroll
        for (int ks = 0; ks < 2; ++ks) {
            union { unsigned int u[4]; bf16x8 s; } bb;
            bb.u[0] = pk[4 * ks]; bb.u[1] = pk[4 * ks + 1];
            bb.u[2] = pk[4 * ks + 2]; bb.u[3] = pk[4 * ks + 3];
            #pragma unroll
            for (int vb = 0; vb < 16; ++vb) {
                int r = vb * 16 + c;
                int u0 = (r * 64 + ks * 32 + 4 * g) ^ ((c & 7) << 3);
                int u1 = (r * 64 + ks * 32 + 16 + 4 * g) ^ ((c & 7) << 3);
                union { bf16x4 h[2]; bf16x8 s; } av;
                av.h[0] = *(const bf16x4*)&Vts[u0];
                av.h[1] = *(const bf16x4*)&Vts[u1];
                o[vb] = __builtin_amdgcn_mfma_f32_16x16x32_bf16(av.s, bb.s, o[vb], 0, 0, 0);
            }
        }
    };

    issueH(hA, 0);
    #pragma unroll 1
    for (int tt = 0; tt < NTILE; tt += 2) {
        __syncthreads();              // waves done reading LDS[t-1]
        stageKV(tt);
        __syncthreads();              // vmcnt(0) drains gll here
        issueH(hB, tt + 1);
        compute(hA);
        __syncthreads();
        stageKV(tt + 1);
        __syncthreads();
        if (tt + 2 < NTILE) issueH(hA, tt + 2);
        compute(hB);
    }

    // epilogue: bf16-pair packed, v-major partials for coalesced stores
    size_t base = (size_t)ch * (DV / 2) * NE;
    #pragma unroll
    for (int vb = 0; vb < 16; ++vb)
        #pragma unroll
        for (int ip = 0; ip < 2; ++ip) {
            union { __hip_bfloat162 h; unsigned int u; } cv;
            cv.h = __float22bfloat162_rn(make_float2(o[vb][2 * ip], o[vb][2 * ip + 1]));
            pacc[base + (size_t)(vb * 8 + 2 * g + ip) * NE + eW] = cv.u;
        }
    if (g == 0) {
        pm[ch * NE + eW] = m;
        pl[ch * NE + eW] = l;
    }
}

// ---------------------------------------------------------------------------
// combine: merge 16 chunk partials (bf16 pairs), LDS-transpose for coalesced
// fp32 writes.  grid: 256 blocks = 64 edge-tiles x 4 v-tiles.
// ---------------------------------------------------------------------------
__global__ __launch_bounds__(256, 4) void combine_kernel(
    const unsigned int* __restrict__ pacc, const float* __restrict__ pm,
    const float* __restrict__ pl, float* __restrict__ out) {

    __shared__ float T[64][68];
    int bid = blockIdx.x;
    int eb = bid & 63, vb = bid >> 6;
    int e0 = eb * 64, v0 = vb * 64;
    int tid = threadIdx.x;
    int el = tid & 63, vh = tid >> 6;
    int e = e0 + el;

    float mv[NCHUNK]; float M = -1e30f;
    #pragma unroll
    for (int chn = 0; chn < NCHUNK; ++chn) {
        mv[chn] = pm[chn * NE + e];
        M = fmaxf(M, mv[chn]);
    }
    float den = 0.0f; float wch[NCHUNK];
    #pragma unroll
    for (int chn = 0; chn < NCHUNK; ++chn) {
        wch[chn] = exp2f(mv[chn] - M);            // log2 units
        den += wch[chn] * pl[chn * NE + e];
    }
    float rden = 1.0f / den;

    #pragma unroll
    for (int kp = 0; kp < 8; ++kp) {
        int vp = vb * 32 + vh * 8 + kp;           // global v-pair index
        float n0 = 0.0f, n1 = 0.0f;
        #pragma unroll
        for (int chn = 0; chn < NCHUNK; ++chn) {
            unsigned int pk = pacc[((size_t)chn * (DV / 2) + vp) * NE + e];
            n0 += wch[chn] * __uint_as_float(pk << 16);
            n1 += wch[chn] * __uint_as_float(pk & 0xffff0000u);
        }
        T[el][(vh * 8 + kp) * 2]     = n0 * rden;
        T[el][(vh * 8 + kp) * 2 + 1] = n1 * rden;
    }
    __syncthreads();

    int er = tid >> 2, c16 = (tid & 3) * 16;
    #pragma unroll
    for (int j = 0; j < 4; ++j) {
        float4 vv = *(const float4*)&T[er][c16 + 4 * j];
        *(float4*)&out[(size_t)(e0 + er) * DV + v0 + c16 + 4 * j] = vv;
    }
}

// ---------------------------------------------------------------------------
// workspace layout (bytes)  — total ≈ 38.0 MB
// ---------------------------------------------------------------------------
#define QB_OFF   ((size_t)0)
#define KB_OFF   (QB_OFF + (size_t)NE * DK * 2)                  // 524288
#define VT_OFF   (KB_OFF + (size_t)NS * DK * 2)                  // 1572864
#define PACC_OFF (VT_OFF + (size_t)DV * NS * 2)                  // 5767168
#define PM_OFF   (PACC_OFF + (size_t)NCHUNK * (DV / 2) * NE * 4) // 39321600
#define PL_OFF   (PM_OFF + (size_t)NCHUNK * NE * 4)              // 39583744

extern "C" void kernel_launch(void* const* d_in, const int* in_sizes, int n_in,
                              void* d_out, int out_size, void* d_ws, size_t ws_size,
                              hipStream_t stream) {
    const float* X  = (const float*)d_in[0];
    const float* Y  = (const float*)d_in[1];
    const int*   H  = (const int*)d_in[2];
    const float* Wq = (const float*)d_in[3];
    const float* Wk = (const float*)d_in[4];
    const float* Wv = (const float*)d_in[5];

    char* ws = (char*)d_ws;
    unsigned short* Qb = (unsigned short*)(ws + QB_OFF);
    unsigned short* Kb = (unsigned short*)(ws + KB_OFF);
    unsigned short* Vt = (unsigned short*)(ws + VT_OFF);
    unsigned int* pacc = (unsigned int*)(ws + PACC_OFF);
    float* pm   = (float*)(ws + PM_OFF);
    float* pl   = (float*)(ws + PL_OFF);

    proj_kernel<<<704, 256, 0, stream>>>(X, Y, Wq, Wk, Wv, Qb, Kb, Vt);
    flash_kernel<<<1024, 256, 0, stream>>>(Qb, Kb, Vt, H, pacc, pm, pl);
    combine_kernel<<<256, 256, 0, stream>>>(pacc, pm, pl, (float*)d_out);
}

// Round 3
// 496.124 us; speedup vs baseline: 1.5646x; 1.5646x over previous
//
#include <hip/hip_runtime.h>
#include <hip/hip_bf16.h>

#define NS 8192
#define NE 4096
#define DIN 512
#define DK 64
#define DV 256
#define NCHUNK 8
#define CHUNK (NS / NCHUNK)   // 1024
#define NTILE (CHUNK / 64)    // 16

typedef __attribute__((ext_vector_type(8))) short bf16x8;
typedef __attribute__((ext_vector_type(4))) short bf16x4;
typedef __attribute__((ext_vector_type(4))) float f32x4;
typedef __attribute__((ext_vector_type(8))) unsigned short ushort8;
typedef __attribute__((ext_vector_type(4))) unsigned short ushort4v;

#define L2E 1.44269504088896f

__device__ __forceinline__ unsigned short f2bf(float f) {
    union { float f; unsigned int u; } v; v.f = f;
    unsigned int u = v.u;
    unsigned int r = u + 0x7fffu + ((u >> 16) & 1u);   // RNE
    return (unsigned short)(r >> 16);
}

// ---------------------------------------------------------------------------
// proj: fused Q/K/V projections.  C = A(fp32,Mx512) @ B(fp32,512xN) -> bf16.
// blocks 0..63: Q = Y@Wq * 0.125*log2e -> Qb[4096][64]   (scores in log2 units)
// blocks 64..191: K = X@Wk            -> Kb[8192][64]
// blocks 192..703: V = X@Wv           -> Vt[256][8192]  (transposed epilogue)
// ---------------------------------------------------------------------------
union ProjSmem {
    struct { unsigned short As[64][40]; unsigned short Bst[64][40]; } s;
    unsigned short Ct[64][72];
};

__global__ __launch_bounds__(256, 4) void proj_kernel(
    const float* __restrict__ X, const float* __restrict__ Y,
    const float* __restrict__ Wq, const float* __restrict__ Wk,
    const float* __restrict__ Wv,
    unsigned short* __restrict__ Qb, unsigned short* __restrict__ Kb,
    unsigned short* __restrict__ Vt) {

    int b = blockIdx.x;
    const float* A; const float* B; unsigned short* out;
    int N, m0, n0; float scale; bool tr;
    if (b < 64)       { A = Y; B = Wq; out = Qb; N = 64;  m0 = b * 64;        n0 = 0;            scale = 0.125f * L2E; tr = false; }
    else if (b < 192) { A = X; B = Wk; out = Kb; N = 64;  m0 = (b - 64) * 64; n0 = 0;            scale = 1.0f;         tr = false; }
    else              { int bb = b - 192;
                        A = X; B = Wv; out = Vt; N = 256; m0 = (bb >> 2) * 64; n0 = (bb & 3) * 64; scale = 1.0f;       tr = true; }

    __shared__ ProjSmem sm;
    int tid = threadIdx.x;
    int lane = tid & 63, w = tid >> 6;
    int c = lane & 15, g = lane >> 4;
    int wr = w >> 1, wc = w & 1;

    f32x4 acc[2][2] = {};

    for (int kt = 0; kt < 16; ++kt) {
        int k0 = kt * 32;
        __syncthreads();
        #pragma unroll
        for (int it = 0; it < 2; ++it) {
            int idx = it * 256 + tid;
            {   // stage A tile: 64 rows x 32 k, fp32 -> bf16
                int r = idx >> 3, c4 = (idx & 7) * 4;
                float4 v = *(const float4*)&A[(size_t)(m0 + r) * DIN + k0 + c4];
                ushort4v t; t.x = f2bf(v.x); t.y = f2bf(v.y); t.z = f2bf(v.z); t.w = f2bf(v.w);
                *(ushort4v*)&sm.s.As[r][c4] = t;
            }
            {   // stage B tile transposed: Bst[n][k]
                int kk = idx >> 4, c4 = (idx & 15) * 4;
                float4 v = *(const float4*)&B[(size_t)(k0 + kk) * N + n0 + c4];
                sm.s.Bst[c4 + 0][kk] = f2bf(v.x);
                sm.s.Bst[c4 + 1][kk] = f2bf(v.y);
                sm.s.Bst[c4 + 2][kk] = f2bf(v.z);
                sm.s.Bst[c4 + 3][kk] = f2bf(v.w);
            }
        }
        __syncthreads();

        bf16x8 af[2], bfr[2];
        #pragma unroll
        for (int fr = 0; fr < 2; ++fr)
            af[fr] = *(const bf16x8*)&sm.s.As[wr * 32 + fr * 16 + c][8 * g];
        #pragma unroll
        for (int fc = 0; fc < 2; ++fc)
            bfr[fc] = *(const bf16x8*)&sm.s.Bst[wc * 32 + fc * 16 + c][8 * g];
        #pragma unroll
        for (int fr = 0; fr < 2; ++fr)
            #pragma unroll
            for (int fc = 0; fc < 2; ++fc)
                acc[fr][fc] = __builtin_amdgcn_mfma_f32_16x16x32_bf16(af[fr], bfr[fc], acc[fr][fc], 0, 0, 0);
    }

    if (!tr) {
        #pragma unroll
        for (int fr = 0; fr < 2; ++fr)
            #pragma unroll
            for (int fc = 0; fc < 2; ++fc)
                #pragma unroll
                for (int i = 0; i < 4; ++i) {
                    int row = wr * 32 + fr * 16 + 4 * g + i;
                    int col = wc * 32 + fc * 16 + c;
                    out[(size_t)(m0 + row) * N + n0 + col] = f2bf(acc[fr][fc][i] * scale);
                }
    } else {
        __syncthreads();
        #pragma unroll
        for (int fr = 0; fr < 2; ++fr)
            #pragma unroll
            for (int fc = 0; fc < 2; ++fc)
                #pragma unroll
                for (int i = 0; i < 4; ++i) {
                    int row = wr * 32 + fr * 16 + 4 * g + i;   // m (sample)
                    int col = wc * 32 + fc * 16 + c;           // n (vdim)
                    sm.Ct[col][row] = f2bf(acc[fr][fc][i]);
                }
        __syncthreads();
        int nl = tid >> 2, c16 = (tid & 3) * 16;
        ushort8 a0 = *(const ushort8*)&sm.Ct[nl][c16];
        ushort8 a1 = *(const ushort8*)&sm.Ct[nl][c16 + 8];
        *(ushort8*)&out[(size_t)(n0 + nl) * NS + m0 + c16] = a0;
        *(ushort8*)&out[(size_t)(n0 + nl) * NS + m0 + c16 + 8] = a1;
    }
}

// ---------------------------------------------------------------------------
// flash: S^T = K·Q^T per wave (16 edges).  XOR-swizzled LDS (T2), staging via
// global_load_lds w/ pre-swizzled source (rule #21), H prefetched 1 tile
// ahead into double-buffered regs (T14).  Partials: bf16-pair packed, v-major.
// grid: 512 blocks = 64 edge-tiles x 8 sample-chunks.
// NOTE: __launch_bounds__(256,2) — (256,3) caps VGPRs at ~170 and spills the
// 64-reg o[] accumulator -> 2 GB of scratch traffic (round-2 post-mortem).
// ---------------------------------------------------------------------------
__global__ __launch_bounds__(256, 2) void flash_kernel(
    const unsigned short* __restrict__ Qb, const unsigned short* __restrict__ Kb,
    const unsigned short* __restrict__ Vt, const int* __restrict__ H,
    unsigned int* __restrict__ pacc, float* __restrict__ pm, float* __restrict__ pl) {

    int bid = blockIdx.x;
    int eb = bid & 63, ch = bid >> 6;
    int e0 = eb * 64;
    int sbeg = ch * CHUNK;

    __shared__ unsigned short Ks[64 * 64];    // 8 KB, row stride 128B, XOR-swizzled
    __shared__ unsigned short Vts[256 * 64];  // 32 KB, row stride 128B, XOR-swizzled

    int tid = threadIdx.x, lane = tid & 63, w = tid >> 6;
    int c = lane & 15, g = lane >> 4;
    int eW = e0 + w * 16 + c;   // this lane's edge column

    bf16x8 qf[2];
    #pragma unroll
    for (int ks = 0; ks < 2; ++ks)
        qf[ks] = *(const bf16x8*)&Qb[(size_t)eW * DK + ks * 32 + 8 * g];

    f32x4 o[16] = {};
    float m = -1e30f, l = 0.0f;

    int hA[16], hB[16];

    // staging: linear LDS dest (wave-uniform base + lane*16B), source column
    // pre-swizzled by (row&7) so the swizzled read below sees the right data.
    auto stageKV = [&](int t) {
        int s0 = sbeg + t * 64;
        int cc = tid & 7;
        #pragma unroll
        for (int it = 0; it < 2; ++it) {
            int r = (it * 256 + tid) >> 3;
            int cs = cc ^ (r & 7);
            __builtin_amdgcn_global_load_lds(
                (const void*)&Kb[(size_t)(s0 + r) * DK + cs * 8],
                (void*)((char*)Ks + (it * 256 + w * 64) * 16), 16, 0, 0);
        }
        #pragma unroll
        for (int it = 0; it < 8; ++it) {
            int v = (it * 256 + tid) >> 3;
            int cs = cc ^ (v & 7);
            __builtin_amdgcn_global_load_lds(
                (const void*)&Vt[(size_t)v * NS + s0 + cs * 8],
                (void*)((char*)Vts + (it * 256 + w * 64) * 16), 16, 0, 0);
        }
    };

    auto issueH = [&](int (&hv)[16], int t) {
        int s0 = sbeg + t * 64;
        #pragma unroll
        for (int fr = 0; fr < 4; ++fr)
            #pragma unroll
            for (int i = 0; i < 4; ++i)
                hv[fr * 4 + i] = H[(size_t)(s0 + fr * 16 + 4 * g + i) * NE + eW];
    };

    auto compute = [&](const int (&hv)[16]) {
        // S^T tile: rows = samples, cols = this wave's 16 edges
        f32x4 st[4] = {};
        #pragma unroll
        for (int ks = 0; ks < 2; ++ks)
            #pragma unroll
            for (int fr = 0; fr < 4; ++fr) {
                int u = ((fr * 16 + c) * 64 + ks * 32 + 8 * g) ^ ((c & 7) << 3);
                bf16x8 a = *(const bf16x8*)&Ks[u];
                st[fr] = __builtin_amdgcn_mfma_f32_16x16x32_bf16(a, qf[ks], st[fr], 0, 0, 0);
            }

        // mask + per-edge tile max (reduce over g via shfl_xor 16/32)
        float pmax = -1e30f;
        #pragma unroll
        for (int fr = 0; fr < 4; ++fr)
            #pragma unroll
            for (int i = 0; i < 4; ++i) {
                float sv = hv[fr * 4 + i] ? st[fr][i] : -1e30f;
                st[fr][i] = sv;
                pmax = fmaxf(pmax, sv);
            }
        pmax = fmaxf(pmax, __shfl_xor(pmax, 16));
        pmax = fmaxf(pmax, __shfl_xor(pmax, 32));

        // defer-max rescale (THR=8 in log2 units -> P <= 256)
        if (!__all(pmax <= m + 8.0f)) {
            float mn = fmaxf(m, pmax);
            float al = exp2f(m - mn);
            l *= al;
            #pragma unroll
            for (int vb = 0; vb < 16; ++vb) o[vb] *= al;
            m = mn;
        }

        float lp = 0.0f;
        #pragma unroll
        for (int fr = 0; fr < 4; ++fr)
            #pragma unroll
            for (int i = 0; i < 4; ++i) {
                float e = exp2f(st[fr][i] - m);   // scores already in log2 units
                st[fr][i] = e;
                lp += e;
            }
        lp += __shfl_xor(lp, 16);
        lp += __shfl_xor(lp, 32);
        l += lp;

        // pack P to bf16 pairs (lane-local)
        unsigned int pk[8];
        #pragma unroll
        for (int fr = 0; fr < 4; ++fr)
            #pragma unroll
            for (int hf = 0; hf < 2; ++hf) {
                union { __hip_bfloat162 h; unsigned int u; } cv;
                cv.h = __float22bfloat162_rn(make_float2(st[fr][2 * hf], st[fr][2 * hf + 1]));
                pk[fr * 2 + hf] = cv.u;
            }

        // PV: out^T[v][e]; A = Vts rows (two b64 reads realize the k-slot perm)
        #pragma unroll
        for (int ks = 0; ks < 2; ++ks) {
            union { unsigned int u[4]; bf16x8 s; } bb;
            bb.u[0] = pk[4 * ks]; bb.u[1] = pk[4 * ks + 1];
            bb.u[2] = pk[4 * ks + 2]; bb.u[3] = pk[4 * ks + 3];
            #pragma unroll
            for (int vb = 0; vb < 16; ++vb) {
                int r = vb * 16 + c;
                int u0 = (r * 64 + ks * 32 + 4 * g) ^ ((c & 7) << 3);
                int u1 = (r * 64 + ks * 32 + 16 + 4 * g) ^ ((c & 7) << 3);
                union { bf16x4 h[2]; bf16x8 s; } av;
                av.h[0] = *(const bf16x4*)&Vts[u0];
                av.h[1] = *(const bf16x4*)&Vts[u1];
                o[vb] = __builtin_amdgcn_mfma_f32_16x16x32_bf16(av.s, bb.s, o[vb], 0, 0, 0);
            }
        }
    };

    issueH(hA, 0);
    #pragma unroll 1
    for (int tt = 0; tt < NTILE; tt += 2) {
        __syncthreads();              // waves done reading LDS[t-1]
        stageKV(tt);
        __syncthreads();              // vmcnt(0) drains gll + hA here
        issueH(hB, tt + 1);           // hB hides under compute(hA) + stage(tt+1)
        compute(hA);
        __syncthreads();
        stageKV(tt + 1);
        __syncthreads();
        if (tt + 2 < NTILE) issueH(hA, tt + 2);
        compute(hB);
    }

    // epilogue: bf16-pair packed, v-major partials for coalesced stores
    size_t base = (size_t)ch * (DV / 2) * NE;
    #pragma unroll
    for (int vb = 0; vb < 16; ++vb)
        #pragma unroll
        for (int ip = 0; ip < 2; ++ip) {
            union { __hip_bfloat162 h; unsigned int u; } cv;
            cv.h = __float22bfloat162_rn(make_float2(o[vb][2 * ip], o[vb][2 * ip + 1]));
            pacc[base + (size_t)(vb * 8 + 2 * g + ip) * NE + eW] = cv.u;
        }
    if (g == 0) {
        pm[ch * NE + eW] = m;
        pl[ch * NE + eW] = l;
    }
}

// ---------------------------------------------------------------------------
// combine: merge 8 chunk partials (bf16 pairs), LDS-transpose for coalesced
// fp32 writes.  grid: 256 blocks = 64 edge-tiles x 4 v-tiles.
// ---------------------------------------------------------------------------
__global__ __launch_bounds__(256, 4) void combine_kernel(
    const unsigned int* __restrict__ pacc, const float* __restrict__ pm,
    const float* __restrict__ pl, float* __restrict__ out) {

    __shared__ float T[64][68];
    int bid = blockIdx.x;
    int eb = bid & 63, vb = bid >> 6;
    int e0 = eb * 64, v0 = vb * 64;
    int tid = threadIdx.x;
    int el = tid & 63, vh = tid >> 6;
    int e = e0 + el;

    float mv[NCHUNK]; float M = -1e30f;
    #pragma unroll
    for (int chn = 0; chn < NCHUNK; ++chn) {
        mv[chn] = pm[chn * NE + e];
        M = fmaxf(M, mv[chn]);
    }
    float den = 0.0f; float wch[NCHUNK];
    #pragma unroll
    for (int chn = 0; chn < NCHUNK; ++chn) {
        wch[chn] = exp2f(mv[chn] - M);            // log2 units
        den += wch[chn] * pl[chn * NE + e];
    }
    float rden = 1.0f / den;

    #pragma unroll
    for (int kp = 0; kp < 8; ++kp) {
        int vp = vb * 32 + vh * 8 + kp;           // global v-pair index
        float n0 = 0.0f, n1 = 0.0f;
        #pragma unroll
        for (int chn = 0; chn < NCHUNK; ++chn) {
            unsigned int pk = pacc[((size_t)chn * (DV / 2) + vp) * NE + e];
            n0 += wch[chn] * __uint_as_float(pk << 16);
            n1 += wch[chn] * __uint_as_float(pk & 0xffff0000u);
        }
        T[el][(vh * 8 + kp) * 2]     = n0 * rden;
        T[el][(vh * 8 + kp) * 2 + 1] = n1 * rden;
    }
    __syncthreads();

    int er = tid >> 2, c16 = (tid & 3) * 16;
    #pragma unroll
    for (int j = 0; j < 4; ++j) {
        float4 vv = *(const float4*)&T[er][c16 + 4 * j];
        *(float4*)&out[(size_t)(e0 + er) * DV + v0 + c16 + 4 * j] = vv;
    }
}

// ---------------------------------------------------------------------------
// workspace layout (bytes)  — total ≈ 22.8 MB
// ---------------------------------------------------------------------------
#define QB_OFF   ((size_t)0)
#define KB_OFF   (QB_OFF + (size_t)NE * DK * 2)                  // 524288
#define VT_OFF   (KB_OFF + (size_t)NS * DK * 2)                  // 1572864
#define PACC_OFF (VT_OFF + (size_t)DV * NS * 2)                  // 5767168
#define PM_OFF   (PACC_OFF + (size_t)NCHUNK * (DV / 2) * NE * 4) // 22544384
#define PL_OFF   (PM_OFF + (size_t)NCHUNK * NE * 4)              // 22675456

extern "C" void kernel_launch(void* const* d_in, const int* in_sizes, int n_in,
                              void* d_out, int out_size, void* d_ws, size_t ws_size,
                              hipStream_t stream) {
    const float* X  = (const float*)d_in[0];
    const float* Y  = (const float*)d_in[1];
    const int*   H  = (const int*)d_in[2];
    const float* Wq = (const float*)d_in[3];
    const float* Wk = (const float*)d_in[4];
    const float* Wv = (const float*)d_in[5];

    char* ws = (char*)d_ws;
    unsigned short* Qb = (unsigned short*)(ws + QB_OFF);
    unsigned short* Kb = (unsigned short*)(ws + KB_OFF);
    unsigned short* Vt = (unsigned short*)(ws + VT_OFF);
    unsigned int* pacc = (unsigned int*)(ws + PACC_OFF);
    float* pm   = (float*)(ws + PM_OFF);
    float* pl   = (float*)(ws + PL_OFF);

    proj_kernel<<<704, 256, 0, stream>>>(X, Y, Wq, Wk, Wv, Qb, Kb, Vt);
    flash_kernel<<<512, 256, 0, stream>>>(Qb, Kb, Vt, H, pacc, pm, pl);
    combine_kernel<<<256, 256, 0, stream>>>(pacc, pm, pl, (float*)d_out);
}

// Round 4
// 80.186 us; speedup vs baseline: 9.6805x; 6.1872x over previous
//
#include <hip/hip_runtime.h>
#include <hip/hip_bf16.h>

#define NS 8192
#define NE 4096
#define DIN 512
#define DK 64
#define DV 256
#define NCHUNK 8
#define CHUNK (NS / NCHUNK)   // 1024
#define NTILE (CHUNK / 64)    // 16

typedef __attribute__((ext_vector_type(8))) short bf16x8;
typedef __attribute__((ext_vector_type(4))) float f32x4;
typedef __attribute__((ext_vector_type(8))) unsigned short ushort8;
typedef __attribute__((ext_vector_type(4))) unsigned short ushort4v;

#define L2E 1.44269504088896f

__device__ __forceinline__ unsigned short f2bf(float f) {
    union { float f; unsigned int u; } v; v.f = f;
    unsigned int u = v.u;
    unsigned int r = u + 0x7fffu + ((u >> 16) & 1u);   // RNE
    return (unsigned short)(r >> 16);
}

// ---------------------------------------------------------------------------
// proj: fused Q/K/V projections.  C = A(fp32,Mx512) @ B(fp32,512xN) -> bf16.
// blocks 0..63: Q = Y@Wq * 0.125*log2e -> Qb[4096][64]   (scores in log2 units)
// blocks 64..191: K = X@Wk            -> Kb[8192][64]
// blocks 192..703: V = X@Wv           -> Vt[256][8192]  (transposed epilogue;
//   sample order PERMUTED within each 64-block so flash PV reads one b128:
//   granule position ks*32+8g+4h+i holds sample ks*32+h*16+4g+i)
// ---------------------------------------------------------------------------
union ProjSmem {
    struct { unsigned short As[64][40]; unsigned short Bst[64][40]; } s;
    unsigned short Ct[64][72];
};

__global__ __launch_bounds__(256, 4) void proj_kernel(
    const float* __restrict__ X, const float* __restrict__ Y,
    const float* __restrict__ Wq, const float* __restrict__ Wk,
    const float* __restrict__ Wv,
    unsigned short* __restrict__ Qb, unsigned short* __restrict__ Kb,
    unsigned short* __restrict__ Vt) {

    int b = blockIdx.x;
    const float* A; const float* B; unsigned short* out;
    int N, m0, n0; float scale; bool tr;
    if (b < 64)       { A = Y; B = Wq; out = Qb; N = 64;  m0 = b * 64;        n0 = 0;            scale = 0.125f * L2E; tr = false; }
    else if (b < 192) { A = X; B = Wk; out = Kb; N = 64;  m0 = (b - 64) * 64; n0 = 0;            scale = 1.0f;         tr = false; }
    else              { int bb = b - 192;
                        A = X; B = Wv; out = Vt; N = 256; m0 = (bb >> 2) * 64; n0 = (bb & 3) * 64; scale = 1.0f;       tr = true; }

    __shared__ ProjSmem sm;
    int tid = threadIdx.x;
    int lane = tid & 63, w = tid >> 6;
    int c = lane & 15, g = lane >> 4;
    int wr = w >> 1, wc = w & 1;

    f32x4 acc[2][2] = {};

    for (int kt = 0; kt < 16; ++kt) {
        int k0 = kt * 32;
        __syncthreads();
        #pragma unroll
        for (int it = 0; it < 2; ++it) {
            int idx = it * 256 + tid;
            {   // stage A tile: 64 rows x 32 k, fp32 -> bf16
                int r = idx >> 3, c4 = (idx & 7) * 4;
                float4 v = *(const float4*)&A[(size_t)(m0 + r) * DIN + k0 + c4];
                ushort4v t; t.x = f2bf(v.x); t.y = f2bf(v.y); t.z = f2bf(v.z); t.w = f2bf(v.w);
                *(ushort4v*)&sm.s.As[r][c4] = t;
            }
            {   // stage B tile transposed: Bst[n][k]
                int kk = idx >> 4, c4 = (idx & 15) * 4;
                float4 v = *(const float4*)&B[(size_t)(k0 + kk) * N + n0 + c4];
                sm.s.Bst[c4 + 0][kk] = f2bf(v.x);
                sm.s.Bst[c4 + 1][kk] = f2bf(v.y);
                sm.s.Bst[c4 + 2][kk] = f2bf(v.z);
                sm.s.Bst[c4 + 3][kk] = f2bf(v.w);
            }
        }
        __syncthreads();

        bf16x8 af[2], bfr[2];
        #pragma unroll
        for (int fr = 0; fr < 2; ++fr)
            af[fr] = *(const bf16x8*)&sm.s.As[wr * 32 + fr * 16 + c][8 * g];
        #pragma unroll
        for (int fc = 0; fc < 2; ++fc)
            bfr[fc] = *(const bf16x8*)&sm.s.Bst[wc * 32 + fc * 16 + c][8 * g];
        #pragma unroll
        for (int fr = 0; fr < 2; ++fr)
            #pragma unroll
            for (int fc = 0; fc < 2; ++fc)
                acc[fr][fc] = __builtin_amdgcn_mfma_f32_16x16x32_bf16(af[fr], bfr[fc], acc[fr][fc], 0, 0, 0);
    }

    if (!tr) {
        #pragma unroll
        for (int fr = 0; fr < 2; ++fr)
            #pragma unroll
            for (int fc = 0; fc < 2; ++fc)
                #pragma unroll
                for (int i = 0; i < 4; ++i) {
                    int row = wr * 32 + fr * 16 + 4 * g + i;
                    int col = wc * 32 + fc * 16 + c;
                    out[(size_t)(m0 + row) * N + n0 + col] = f2bf(acc[fr][fc][i] * scale);
                }
    } else {
        __syncthreads();
        #pragma unroll
        for (int fr = 0; fr < 2; ++fr)
            #pragma unroll
            for (int fc = 0; fc < 2; ++fc)
                #pragma unroll
                for (int i = 0; i < 4; ++i) {
                    int row = wr * 32 + fr * 16 + 4 * g + i;   // m (sample)
                    int col = wc * 32 + fc * 16 + c;           // n (vdim)
                    sm.Ct[col][row] = f2bf(acc[fr][fc][i]);
                }
        __syncthreads();
        // permuted granule writes: out pos 8G+j holds sample ks*32+(j>>2)*16+4*gq+(j&3)
        int nl = tid >> 2, q = tid & 3;
        #pragma unroll
        for (int gg = 0; gg < 2; ++gg) {
            int G = q * 2 + gg;
            int ks = G >> 2, gq = G & 3;
            union { ushort4v h[2]; ushort8 v8; } u;
            u.h[0] = *(const ushort4v*)&sm.Ct[nl][ks * 32 + gq * 4];
            u.h[1] = *(const ushort4v*)&sm.Ct[nl][ks * 32 + 16 + gq * 4];
            *(ushort8*)&out[(size_t)(n0 + nl) * NS + m0 + G * 8] = u.v8;
        }
    }
}

// ---------------------------------------------------------------------------
// flash: S^T = K·Q^T per wave (16 edges).  Flat single loop (round-1 register
// footprint — no lambdas / no H double-buffer: those spilled o[16] in r2/r3).
// XOR-swizzled LDS (T2) + global_load_lds w/ pre-swizzled source (rule #21).
// XCD-aware decode (T1): ch = bid&7 -> each XCD owns one chunk, K/V slice
// (640 KB) stays in its 4 MB L2.  Partials bf16-pair packed, v-major.
// grid: 512 blocks = 8 chunks x 64 edge-tiles.
// ---------------------------------------------------------------------------
__global__ __launch_bounds__(256, 2) void flash_kernel(
    const unsigned short* __restrict__ Qb, const unsigned short* __restrict__ Kb,
    const unsigned short* __restrict__ Vt, const int* __restrict__ H,
    unsigned int* __restrict__ pacc, float* __restrict__ pm, float* __restrict__ pl) {

    int bid = blockIdx.x;
    int ch = bid & 7, eb = bid >> 3;      // XCD-aware: bid%8 ~ XCD id
    int e0 = eb * 64;
    int sbeg = ch * CHUNK;

    __shared__ unsigned short Ks[64 * 64];    // 8 KB, XOR-swizzled granules
    __shared__ unsigned short Vts[256 * 64];  // 32 KB, XOR-swizzled granules

    int tid = threadIdx.x, lane = tid & 63, w = tid >> 6;
    int c = lane & 15, g = lane >> 4;
    int eW = e0 + w * 16 + c;   // this lane's edge column
    int cc = tid & 7;

    bf16x8 qf[2];
    #pragma unroll
    for (int ks = 0; ks < 2; ++ks)
        qf[ks] = *(const bf16x8*)&Qb[(size_t)eW * DK + ks * 32 + 8 * g];

    f32x4 o[16] = {};
    float m = -1e30f, l = 0.0f;

    #pragma unroll 1
    for (int t = 0; t < NTILE; ++t) {
        int s0 = sbeg + t * 64;

        __syncthreads();   // waves done reading LDS[t-1]

        // stage K (2) + V (8) via global_load_lds: linear dest, source granule
        // pre-swizzled by row&7 (involution matches the read-side XOR).
        #pragma unroll
        for (int it = 0; it < 2; ++it) {
            int idx = it * 256 + tid;
            int r = idx >> 3;
            int cs = cc ^ (r & 7);
            __builtin_amdgcn_global_load_lds(
                (const void*)&Kb[(size_t)(s0 + r) * DK + cs * 8],
                (void*)((char*)Ks + (it * 256 + w * 64) * 16), 16, 0, 0);
        }
        #pragma unroll
        for (int it = 0; it < 8; ++it) {
            int idx = it * 256 + tid;
            int v = idx >> 3;
            int cs = cc ^ (v & 7);
            __builtin_amdgcn_global_load_lds(
                (const void*)&Vt[(size_t)v * NS + s0 + cs * 8],
                (void*)((char*)Vts + (it * 256 + w * 64) * 16), 16, 0, 0);
        }

        // H mask loads: issue after staging, drain at the same barrier
        int hv[16];
        #pragma unroll
        for (int fr = 0; fr < 4; ++fr)
            #pragma unroll
            for (int i = 0; i < 4; ++i)
                hv[fr * 4 + i] = H[(size_t)(s0 + fr * 16 + 4 * g + i) * NE + eW];

        __syncthreads();   // vmcnt(0) drain: LDS tiles + hv ready

        // S^T tile: rows = samples, cols = this wave's 16 edges
        f32x4 st[4] = {};
        #pragma unroll
        for (int ks = 0; ks < 2; ++ks)
            #pragma unroll
            for (int fr = 0; fr < 4; ++fr) {
                int u = ((fr * 16 + c) * 64 + ks * 32 + 8 * g) ^ ((c & 7) << 3);
                bf16x8 a = *(const bf16x8*)&Ks[u];
                st[fr] = __builtin_amdgcn_mfma_f32_16x16x32_bf16(a, qf[ks], st[fr], 0, 0, 0);
            }

        // mask + per-edge tile max (reduce over g via shfl_xor 16/32)
        float pmax = -1e30f;
        #pragma unroll
        for (int fr = 0; fr < 4; ++fr)
            #pragma unroll
            for (int i = 0; i < 4; ++i) {
                float sv = hv[fr * 4 + i] ? st[fr][i] : -1e30f;
                st[fr][i] = sv;
                pmax = fmaxf(pmax, sv);
            }
        pmax = fmaxf(pmax, __shfl_xor(pmax, 16));
        pmax = fmaxf(pmax, __shfl_xor(pmax, 32));

        // defer-max rescale (THR=8 in log2 units -> P <= 256)
        if (!__all(pmax <= m + 8.0f)) {
            float mn = fmaxf(m, pmax);
            float al = exp2f(m - mn);
            l *= al;
            #pragma unroll
            for (int vb = 0; vb < 16; ++vb) o[vb] *= al;
            m = mn;
        }

        float lp = 0.0f;
        #pragma unroll
        for (int fr = 0; fr < 4; ++fr)
            #pragma unroll
            for (int i = 0; i < 4; ++i) {
                float e = exp2f(st[fr][i] - m);   // scores already in log2 units
                st[fr][i] = e;
                lp += e;
            }
        lp += __shfl_xor(lp, 16);
        lp += __shfl_xor(lp, 32);
        l += lp;

        // pack P to bf16 pairs (lane-local)
        unsigned int pk[8];
        #pragma unroll
        for (int fr = 0; fr < 4; ++fr)
            #pragma unroll
            for (int hf = 0; hf < 2; ++hf) {
                union { __hip_bfloat162 h; unsigned int u; } cv;
                cv.h = __float22bfloat162_rn(make_float2(st[fr][2 * hf], st[fr][2 * hf + 1]));
                pk[fr * 2 + hf] = cv.u;
            }

        // PV: out^T[v][e]; A = one b128 per (ks,vb) — Vt global layout is
        // pre-permuted so the granule already holds the k-slot interleave.
        #pragma unroll
        for (int ks = 0; ks < 2; ++ks) {
            union { unsigned int u[4]; bf16x8 s; } bb;
            bb.u[0] = pk[4 * ks]; bb.u[1] = pk[4 * ks + 1];
            bb.u[2] = pk[4 * ks + 2]; bb.u[3] = pk[4 * ks + 3];
            #pragma unroll
            for (int vb = 0; vb < 16; ++vb) {
                int u = ((vb * 16 + c) * 64 + ks * 32 + 8 * g) ^ ((c & 7) << 3);
                bf16x8 av = *(const bf16x8*)&Vts[u];
                o[vb] = __builtin_amdgcn_mfma_f32_16x16x32_bf16(av, bb.s, o[vb], 0, 0, 0);
            }
        }
    }

    // epilogue: bf16-pair packed, v-major partials for coalesced stores
    size_t base = (size_t)ch * (DV / 2) * NE;
    #pragma unroll
    for (int vb = 0; vb < 16; ++vb)
        #pragma unroll
        for (int ip = 0; ip < 2; ++ip) {
            union { __hip_bfloat162 h; unsigned int u; } cv;
            cv.h = __float22bfloat162_rn(make_float2(o[vb][2 * ip], o[vb][2 * ip + 1]));
            pacc[base + (size_t)(vb * 8 + 2 * g + ip) * NE + eW] = cv.u;
        }
    if (g == 0) {
        pm[ch * NE + eW] = m;
        pl[ch * NE + eW] = l;
    }
}

// ---------------------------------------------------------------------------
// combine: merge 8 chunk partials (bf16 pairs), LDS-transpose for coalesced
// fp32 writes.  grid: 256 blocks = 64 edge-tiles x 4 v-tiles.
// ---------------------------------------------------------------------------
__global__ __launch_bounds__(256, 4) void combine_kernel(
    const unsigned int* __restrict__ pacc, const float* __restrict__ pm,
    const float* __restrict__ pl, float* __restrict__ out) {

    __shared__ float T[64][68];
    int bid = blockIdx.x;
    int eb = bid & 63, vb = bid >> 6;
    int e0 = eb * 64, v0 = vb * 64;
    int tid = threadIdx.x;
    int el = tid & 63, vh = tid >> 6;
    int e = e0 + el;

    float mv[NCHUNK]; float M = -1e30f;
    #pragma unroll
    for (int chn = 0; chn < NCHUNK; ++chn) {
        mv[chn] = pm[chn * NE + e];
        M = fmaxf(M, mv[chn]);
    }
    float den = 0.0f; float wch[NCHUNK];
    #pragma unroll
    for (int chn = 0; chn < NCHUNK; ++chn) {
        wch[chn] = exp2f(mv[chn] - M);            // log2 units
        den += wch[chn] * pl[chn * NE + e];
    }
    float rden = 1.0f / den;

    #pragma unroll
    for (int kp = 0; kp < 8; ++kp) {
        int vp = vb * 32 + vh * 8 + kp;           // global v-pair index
        float n0 = 0.0f, n1 = 0.0f;
        #pragma unroll
        for (int chn = 0; chn < NCHUNK; ++chn) {
            unsigned int pk = pacc[((size_t)chn * (DV / 2) + vp) * NE + e];
            n0 += wch[chn] * __uint_as_float(pk << 16);
            n1 += wch[chn] * __uint_as_float(pk & 0xffff0000u);
        }
        T[el][(vh * 8 + kp) * 2]     = n0 * rden;
        T[el][(vh * 8 + kp) * 2 + 1] = n1 * rden;
    }
    __syncthreads();

    int er = tid >> 2, c16 = (tid & 3) * 16;
    #pragma unroll
    for (int j = 0; j < 4; ++j) {
        float4 vv = *(const float4*)&T[er][c16 + 4 * j];
        *(float4*)&out[(size_t)(e0 + er) * DV + v0 + c16 + 4 * j] = vv;
    }
}

// ---------------------------------------------------------------------------
// workspace layout (bytes)  — total ≈ 22.7 MB
// ---------------------------------------------------------------------------
#define QB_OFF   ((size_t)0)
#define KB_OFF   (QB_OFF + (size_t)NE * DK * 2)                  // 524288
#define VT_OFF   (KB_OFF + (size_t)NS * DK * 2)                  // 1572864
#define PACC_OFF (VT_OFF + (size_t)DV * NS * 2)                  // 5767168
#define PM_OFF   (PACC_OFF + (size_t)NCHUNK * (DV / 2) * NE * 4) // 22544384
#define PL_OFF   (PM_OFF + (size_t)NCHUNK * NE * 4)              // 22675456

extern "C" void kernel_launch(void* const* d_in, const int* in_sizes, int n_in,
                              void* d_out, int out_size, void* d_ws, size_t ws_size,
                              hipStream_t stream) {
    const float* X  = (const float*)d_in[0];
    const float* Y  = (const float*)d_in[1];
    const int*   H  = (const int*)d_in[2];
    const float* Wq = (const float*)d_in[3];
    const float* Wk = (const float*)d_in[4];
    const float* Wv = (const float*)d_in[5];

    char* ws = (char*)d_ws;
    unsigned short* Qb = (unsigned short*)(ws + QB_OFF);
    unsigned short* Kb = (unsigned short*)(ws + KB_OFF);
    unsigned short* Vt = (unsigned short*)(ws + VT_OFF);
    unsigned int* pacc = (unsigned int*)(ws + PACC_OFF);
    float* pm   = (float*)(ws + PM_OFF);
    float* pl   = (float*)(ws + PL_OFF);

    proj_kernel<<<704, 256, 0, stream>>>(X, Y, Wq, Wk, Wv, Qb, Kb, Vt);
    flash_kernel<<<512, 256, 0, stream>>>(Qb, Kb, Vt, H, pacc, pm, pl);
    combine_kernel<<<256, 256, 0, stream>>>(pacc, pm, pl, (float*)d_out);
}